// Round 1
// baseline (200.620 us; speedup 1.0000x reference)
//
#include <hip/hip_runtime.h>
#include <hip/hip_bf16.h>

#define NROW 50000
#define DIN 128
#define DM 256
#define HH 4
#define NC 40
#define BHN 200000
#define NBLK 782   // ceil(50000/64): 64 rows per 4-wave block

typedef float f32x4 __attribute__((ext_vector_type(4)));
typedef short bf16x8 __attribute__((ext_vector_type(8)));

__device__ __forceinline__ unsigned int pk2(float lo, float hi) {
    __hip_bfloat162 h = __float22bfloat162_rn(make_float2(lo, hi));
    return *(unsigned int*)&h;
}

// async 16B/lane global->LDS: lds dest = wave-uniform base + lane*16
__device__ __forceinline__ void gl_lds16(const unsigned short* g, unsigned short* l) {
    __builtin_amdgcn_global_load_lds(
        (const __attribute__((address_space(1))) unsigned int*)(g),
        (__attribute__((address_space(3))) unsigned int*)(l),
        16, 0, 0);
}

// -------- prep: [0,782) scatter | [782,798) Wpk | [798,810) Wgpk | [810,850) bias2+wsum --------
// Wpk  [kc][t][ln][8]: fragment-packed Win^T. Used as the A operand of the
//   swapped phase-1 MFMA (A/B fragment layouts are symmetric -> packing unchanged).
// Wgpk [h][kc][t][ln][8]: fragment-packed gamma*Wh^T with pi-PERMUTED k so the
//   phase-3 A-fragment equals the lane-local packed Y words (no transpose needed):
//   pi(kc,q,j) = kc*32 + (j>>2)*16 + q*4 + (j&3)   (bijective per 32-k tile)
__global__ __launch_bounds__(256) void k_prep(const int* __restrict__ pi,
                                              const float* __restrict__ pv,
                                              const float* __restrict__ Win,
                                              const float* __restrict__ Wh,
                                              const float* __restrict__ gamma,
                                              const float* __restrict__ beta,
                                              const float* __restrict__ bh,
                                              float* __restrict__ vcol,
                                              unsigned short* __restrict__ Wpk,
                                              unsigned short* __restrict__ Wgpk,
                                              float* __restrict__ bias2,
                                              float* __restrict__ wsum) {
    const int bid = blockIdx.x, tid = threadIdx.x;
    if (bid < 782) {
        int k = bid * 256 + tid;
        if (k < BHN) {
            int b = (k >= 150000) ? 3 : (k >= 100000) ? 2 : (k >= 50000) ? 1 : 0;
            int col = pi[2 * BHN + k];
            vcol[b * NROW + col] = pv[k];
        }
    } else if (bid < 798) {
        int base = (bid - 782) * 512;
        #pragma unroll
        for (int qq = 0; qq < 2; ++qq) {
            int s = base + qq * 256 + tid;
            int ln = s & 63;
            int t  = (s >> 6) & 15;
            int kc = s >> 10;
            int n  = t * 16 + (ln & 15);
            int kb = kc * 32 + ((ln >> 4) << 3);
            union { unsigned int ui[4]; uint4 v4; } u;
            #pragma unroll
            for (int jj = 0; jj < 4; ++jj)
                u.ui[jj] = pk2(Win[(kb + 2 * jj) * DM + n], Win[(kb + 2 * jj + 1) * DM + n]);
            *(uint4*)&Wpk[s * 8] = u.v4;
        }
    } else if (bid < 810) {
        int base = (bid - 798) * 512;
        #pragma unroll
        for (int qq = 0; qq < 2; ++qq) {
            int s = base + qq * 256 + tid;
            int ln = s & 63;
            int u6 = s >> 6;
            int t  = u6 % 3;
            int v6 = u6 / 3;
            int kc = v6 & 7;
            int h  = v6 >> 3;
            int c  = t * 16 + (ln & 15);
            int dbase = h * 256 + kc * 32 + ((ln >> 4) << 2);   // h*256 + 32*kc + 4*q
            union { unsigned int ui[4]; uint4 v4; } u;
            if (c < NC) {
                #pragma unroll
                for (int jj = 0; jj < 4; ++jj) {
                    int dA = dbase + ((jj >> 1) << 4) + ((jj & 1) << 1);  // pi row for k-slot 2jj
                    u.ui[jj] = pk2(gamma[dA] * Wh[dA * NC + c],
                                   gamma[dA + 1] * Wh[(dA + 1) * NC + c]);
                }
            } else {
                u.v4 = make_uint4(0u, 0u, 0u, 0u);
            }
            *(uint4*)&Wgpk[s * 8] = u.v4;
        }
    } else {   // bias2[c] = bh[c] + sum_d beta[d]*Wh[d][c] ; wsum[c] = sum_d gamma[d]*Wh[d][c]
        __shared__ float redb[256], redw[256];
        int c = bid - 810;
        float sb = 0.f, sw = 0.f;
        #pragma unroll
        for (int q = 0; q < 4; ++q) {
            int d = tid + 256 * q;
            float w = Wh[d * NC + c];
            sb = fmaf(beta[d], w, sb);
            sw = fmaf(gamma[d], w, sw);
        }
        redb[tid] = sb; redw[tid] = sw;
        __syncthreads();
        for (int st = 128; st > 0; st >>= 1) {
            if (tid < st) { redb[tid] += redb[tid + st]; redw[tid] += redw[tid + st]; }
            __syncthreads();
        }
        if (tid == 0) { bias2[c] = bh[c] + redb[0]; wsum[c] = redw[0]; }
    }
}

// -------- fused: swapped phase-1 MFMA puts one table row per lane; phase 2/3
// fused per head with LN folded into the epilogue. LDS = 32KB stage only. --------
__global__ __launch_bounds__(256, 4) void k_fused(
    const float* __restrict__ feats, const float* __restrict__ appd,
    const unsigned short* __restrict__ Wpk,
    const unsigned short* __restrict__ Wgpk,
    const float* __restrict__ vcol,
    const float* __restrict__ b_in,
    const float* __restrict__ bias2,
    const float* __restrict__ wsum,
    float* __restrict__ out)
{
    __shared__ __align__(16) unsigned short stage[16384];   // 32 KB weight staging

    const int tid = threadIdx.x;
    const int wv = tid >> 6;
    const int ln = tid & 63;
    const int quad = ln >> 4;
    const int lr = ln & 15;
    const int j0 = blockIdx.x * 64;
    const int jw = j0 + wv * 16;
    const int ar = min(jw + lr, NROW - 1);

    // ---- preload + pre-pack ALL feat B-fragments (row ar, k = kc*32+quad*8..+7).
    // No HBM loads inside the barrier-fenced loops -> syncthreads drains are L2-only.
    unsigned int afr[8][4];
    {
        const float* rf = feats + (size_t)ar * DIN;
        const float* ra = appd  + (size_t)ar * DIN;
        #pragma unroll
        for (int kc = 0; kc < 8; ++kc) {
            const float* src = (kc < 4) ? rf : ra;
            const int ko = (kc & 3) * 32 + quad * 8;
            float4 x0 = *(const float4*)(src + ko);
            float4 x1 = *(const float4*)(src + ko + 4);
            afr[kc][0] = pk2(x0.x, x0.y);
            afr[kc][1] = pk2(x0.z, x0.w);
            afr[kc][2] = pk2(x1.x, x1.y);
            afr[kc][3] = pk2(x1.z, x1.w);
        }
    }
    float vm[HH];
    #pragma unroll
    for (int h = 0; h < HH; ++h) vm[h] = vcol[h * NROW + ar];

    const f32x4 zero4 = {0.f, 0.f, 0.f, 0.f};
    f32x4 accG[16];
    #pragma unroll
    for (int t = 0; t < 16; ++t) accG[t] = zero4;

    // ---- phase 1: G = feat @ Win, SWAPPED operands: mfma(Wfrag, featfrag).
    // Result layout: lane(quad,lr) holds G[row jw+lr][col 16t + quad*4 + rg].
    // 4 chunks x 32 frags (32KB), 2 barriers each.
    #pragma unroll 1
    for (int cc = 0; cc < 4; ++cc) {
        __syncthreads();   // previous chunk's LDS reads done
        #pragma unroll
        for (int q = 0; q < 8; ++q) {
            int f = wv * 8 + q;
            gl_lds16(Wpk + ((size_t)((cc * 32 + f) * 64 + ln)) * 8, &stage[f * 512]);
        }
        __syncthreads();   // staging complete (only gl_lds outstanding: L2 latency)
        #pragma unroll
        for (int kcl = 0; kcl < 2; ++kcl) {
            union { unsigned int ui[4]; bf16x8 v; } a;
            a.ui[0] = afr[cc * 2 + kcl][0];
            a.ui[1] = afr[cc * 2 + kcl][1];
            a.ui[2] = afr[cc * 2 + kcl][2];
            a.ui[3] = afr[cc * 2 + kcl][3];
            #pragma unroll
            for (int t = 0; t < 16; ++t) {
                bf16x8 wf = *(const bf16x8*)&stage[((kcl * 16 + t) * 64 + ln) * 8];
                accG[t] = __builtin_amdgcn_mfma_f32_16x16x32_bf16(wf, a.v, accG[t], 0, 0, 0);
            }
        }
    }

    // ---- phase 2+3 fused per head: y = vm*relu(vm*G + b) computed ONCE (f32 G),
    // stats accumulated inline, packed to bf16, fed straight to the head GEMM
    // (pi-permuted Wgpk makes the A-fragment = lane's packed words in order).
    // LN applied in the epilogue: out = rs*acc + nm*wsum + bias2.
    float s_ = 0.f, ss_ = 0.f;
    f32x4 accO[3];
    #pragma unroll
    for (int t = 0; t < 3; ++t) accO[t] = zero4;

    #pragma unroll 1
    for (int h = 0; h < HH; ++h) {
        __syncthreads();   // stage buffer free
        #pragma unroll
        for (int q = 0; q < 6; ++q) {
            int sl = wv * 6 + q;
            gl_lds16(Wgpk + ((size_t)((h * 24 + sl) * 64 + ln)) * 8, &stage[sl * 512]);
        }
        const float vh = vm[h];
        unsigned int ya[16];
        // pass 0: t = 0..8 (covers kc' 0..4); VALU here hides the staging latency
        #pragma unroll
        for (int tt = 0; tt < 8; ++tt) {
            float4 b4 = *(const float4*)&b_in[tt * 16 + quad * 4];
            float y0 = vh * fmaxf(fmaf(vh, accG[tt][0], b4.x), 0.f);
            float y1 = vh * fmaxf(fmaf(vh, accG[tt][1], b4.y), 0.f);
            float y2 = vh * fmaxf(fmaf(vh, accG[tt][2], b4.z), 0.f);
            float y3 = vh * fmaxf(fmaf(vh, accG[tt][3], b4.w), 0.f);
            s_ += (y0 + y1) + (y2 + y3);
            ss_ = fmaf(y0, y0, ss_); ss_ = fmaf(y1, y1, ss_);
            ss_ = fmaf(y2, y2, ss_); ss_ = fmaf(y3, y3, ss_);
            ya[tt * 2]     = pk2(y0, y1);
            ya[tt * 2 + 1] = pk2(y2, y3);
        }
        __syncthreads();   // staging landed
        #pragma unroll
        for (int kcl = 0; kcl < 4; ++kcl) {
            union { unsigned int ui[4]; bf16x8 v; } af;
            af.ui[0] = ya[4 * kcl];     af.ui[1] = ya[4 * kcl + 1];
            af.ui[2] = ya[4 * kcl + 2]; af.ui[3] = ya[4 * kcl + 3];
            #pragma unroll
            for (int t3 = 0; t3 < 3; ++t3) {
                bf16x8 wf = *(const bf16x8*)&stage[((kcl * 3 + t3) * 64 + ln) * 8];
                accO[t3] = __builtin_amdgcn_mfma_f32_16x16x32_bf16(af.v, wf, accO[t3], 0, 0, 0);
            }
        }
        // pass 1: t = 8..16 (kc' 4..8); overlaps with pass-0 MFMAs on the matrix pipe
        #pragma unroll
        for (int tt = 8; tt < 16; ++tt) {
            float4 b4 = *(const float4*)&b_in[tt * 16 + quad * 4];
            float y0 = vh * fmaxf(fmaf(vh, accG[tt][0], b4.x), 0.f);
            float y1 = vh * fmaxf(fmaf(vh, accG[tt][1], b4.y), 0.f);
            float y2 = vh * fmaxf(fmaf(vh, accG[tt][2], b4.z), 0.f);
            float y3 = vh * fmaxf(fmaf(vh, accG[tt][3], b4.w), 0.f);
            s_ += (y0 + y1) + (y2 + y3);
            ss_ = fmaf(y0, y0, ss_); ss_ = fmaf(y1, y1, ss_);
            ss_ = fmaf(y2, y2, ss_); ss_ = fmaf(y3, y3, ss_);
            ya[(tt - 8) * 2]     = pk2(y0, y1);
            ya[(tt - 8) * 2 + 1] = pk2(y2, y3);
        }
        #pragma unroll
        for (int kcl = 4; kcl < 8; ++kcl) {
            union { unsigned int ui[4]; bf16x8 v; } af;
            af.ui[0] = ya[4 * (kcl - 4)];     af.ui[1] = ya[4 * (kcl - 4) + 1];
            af.ui[2] = ya[4 * (kcl - 4) + 2]; af.ui[3] = ya[4 * (kcl - 4) + 3];
            #pragma unroll
            for (int t3 = 0; t3 < 3; ++t3) {
                bf16x8 wf = *(const bf16x8*)&stage[((kcl * 3 + t3) * 64 + ln) * 8];
                accO[t3] = __builtin_amdgcn_mfma_f32_16x16x32_bf16(af.v, wf, accO[t3], 0, 0, 0);
            }
        }
    }

    // ---- epilogue: finish LN stats (row = jw+lr lives on the 4 quad-lanes of lr),
    // fold LN affine: out = rs*acc + nm*wsum + bias2
    s_  += __shfl_xor(s_, 16);  s_  += __shfl_xor(s_, 32);
    ss_ += __shfl_xor(ss_, 16); ss_ += __shfl_xor(ss_, 32);
    float mm  = s_ * (1.f / 1024.f);
    float var = ss_ * (1.f / 1024.f) - mm * mm;
    float rs  = rsqrtf(var + 1e-5f);
    float nm  = -mm * rs;

    float rs_r[4], nm_r[4];
    #pragma unroll
    for (int rg = 0; rg < 4; ++rg) {
        int rloc = quad * 4 + rg;          // lane rloc (quad 0, lr=rloc) has row jw+rloc
        rs_r[rg] = __shfl(rs, rloc);
        nm_r[rg] = __shfl(nm, rloc);
    }
    #pragma unroll
    for (int t = 0; t < 3; ++t) {
        int c = t * 16 + lr;
        if (c < NC) {
            float w2 = wsum[c], b2 = bias2[c];
            #pragma unroll
            for (int rg = 0; rg < 4; ++rg) {
                int row = jw + quad * 4 + rg;
                if (row < NROW)
                    out[(size_t)row * NC + c] = fmaf(rs_r[rg], accO[t][rg], fmaf(nm_r[rg], w2, b2));
            }
        }
    }
}

extern "C" void kernel_launch(void* const* d_in, const int* in_sizes, int n_in,
                              void* d_out, int out_size, void* d_ws, size_t ws_size,
                              hipStream_t stream) {
    const int*   pi    = (const int*)d_in[0];
    const float* pv    = (const float*)d_in[1];
    const float* feats = (const float*)d_in[2];
    const float* appd  = (const float*)d_in[3];
    const float* Win   = (const float*)d_in[4];
    const float* b_in  = (const float*)d_in[5];
    const float* gamma = (const float*)d_in[6];
    const float* beta  = (const float*)d_in[7];
    const float* Wh    = (const float*)d_in[8];
    const float* bh    = (const float*)d_in[9];
    float* out = (float*)d_out;

    char* w = (char*)d_ws;
    float*          vcolW  = (float*)w;                        // 800000 B
    unsigned short* WpkW   = (unsigned short*)(w + 800000);    // 131072 B
    unsigned short* WgpkW  = (unsigned short*)(w + 931072);    // 98304 B
    float*          bias2W = (float*)(w + 1029376);            // 160 B
    float*          wsumW  = (float*)(w + 1029536);            // 160 B

    k_prep<<<850, 256, 0, stream>>>(pi, pv, Win, Wh, gamma, beta, bh,
                                    vcolW, WpkW, WgpkW, bias2W, wsumW);
    k_fused<<<NBLK, 256, 0, stream>>>(feats, appd, WpkW, WgpkW, vcolW, b_in,
                                      bias2W, wsumW, out);
}

// Round 2
// 183.321 us; speedup vs baseline: 1.0944x; 1.0944x over previous
//
#include <hip/hip_runtime.h>
#include <hip/hip_bf16.h>

#define NROW 50000
#define DIN 128
#define DM 256
#define HH 4
#define NC 40
#define BHN 200000
#define NBLK 782   // ceil(50000/64): 64 rows per 4-wave block

typedef float f32x4 __attribute__((ext_vector_type(4)));
typedef short bf16x8 __attribute__((ext_vector_type(8)));

__device__ __forceinline__ unsigned int pk2(float lo, float hi) {
    __hip_bfloat162 h = __float22bfloat162_rn(make_float2(lo, hi));
    return *(unsigned int*)&h;
}

// async 16B/lane global->LDS: lds dest = wave-uniform base + lane*16
__device__ __forceinline__ void gl_lds16(const unsigned short* g, unsigned short* l) {
    __builtin_amdgcn_global_load_lds(
        (const __attribute__((address_space(1))) unsigned int*)(g),
        (__attribute__((address_space(3))) unsigned int*)(l),
        16, 0, 0);
}

// -------- prep: [0,782) scatter | [782,798) Wpk | [798,810) Wgpk | [810,850) bias2+wsum --------
// Wpk  [kc][t][ln][8]: fragment-packed Win^T. Used as the A operand of the
//   swapped phase-1 MFMA (A/B fragment layouts are symmetric -> packing unchanged).
// Wgpk [h][kc][t][ln][8]: fragment-packed gamma*Wh^T with pi-PERMUTED k so the
//   phase-3 A-fragment equals the lane-local packed Y words (no transpose needed):
//   pi(kc,q,j) = kc*32 + (j>>2)*16 + q*4 + (j&3)   (bijective per 32-k tile)
__global__ __launch_bounds__(256) void k_prep(const int* __restrict__ pi,
                                              const float* __restrict__ pv,
                                              const float* __restrict__ Win,
                                              const float* __restrict__ Wh,
                                              const float* __restrict__ gamma,
                                              const float* __restrict__ beta,
                                              const float* __restrict__ bh,
                                              float* __restrict__ vcol,
                                              unsigned short* __restrict__ Wpk,
                                              unsigned short* __restrict__ Wgpk,
                                              float* __restrict__ bias2,
                                              float* __restrict__ wsum) {
    const int bid = blockIdx.x, tid = threadIdx.x;
    if (bid < 782) {
        int k = bid * 256 + tid;
        if (k < BHN) {
            int b = (k >= 150000) ? 3 : (k >= 100000) ? 2 : (k >= 50000) ? 1 : 0;
            int col = pi[2 * BHN + k];
            vcol[b * NROW + col] = pv[k];
        }
    } else if (bid < 798) {
        int base = (bid - 782) * 512;
        #pragma unroll
        for (int qq = 0; qq < 2; ++qq) {
            int s = base + qq * 256 + tid;
            int ln = s & 63;
            int t  = (s >> 6) & 15;
            int kc = s >> 10;
            int n  = t * 16 + (ln & 15);
            int kb = kc * 32 + ((ln >> 4) << 3);
            union { unsigned int ui[4]; uint4 v4; } u;
            #pragma unroll
            for (int jj = 0; jj < 4; ++jj)
                u.ui[jj] = pk2(Win[(kb + 2 * jj) * DM + n], Win[(kb + 2 * jj + 1) * DM + n]);
            *(uint4*)&Wpk[s * 8] = u.v4;
        }
    } else if (bid < 810) {
        int base = (bid - 798) * 512;
        #pragma unroll
        for (int qq = 0; qq < 2; ++qq) {
            int s = base + qq * 256 + tid;
            int ln = s & 63;
            int u6 = s >> 6;
            int t  = u6 % 3;
            int v6 = u6 / 3;
            int kc = v6 & 7;
            int h  = v6 >> 3;
            int c  = t * 16 + (ln & 15);
            int dbase = h * 256 + kc * 32 + ((ln >> 4) << 2);   // h*256 + 32*kc + 4*q
            union { unsigned int ui[4]; uint4 v4; } u;
            if (c < NC) {
                #pragma unroll
                for (int jj = 0; jj < 4; ++jj) {
                    int dA = dbase + ((jj >> 1) << 4) + ((jj & 1) << 1);  // pi row for k-slot 2jj
                    u.ui[jj] = pk2(gamma[dA] * Wh[dA * NC + c],
                                   gamma[dA + 1] * Wh[(dA + 1) * NC + c]);
                }
            } else {
                u.v4 = make_uint4(0u, 0u, 0u, 0u);
            }
            *(uint4*)&Wgpk[s * 8] = u.v4;
        }
    } else {   // bias2[c] = bh[c] + sum_d beta[d]*Wh[d][c] ; wsum[c] = sum_d gamma[d]*Wh[d][c]
        __shared__ float redb[256], redw[256];
        int c = bid - 810;
        float sb = 0.f, sw = 0.f;
        #pragma unroll
        for (int q = 0; q < 4; ++q) {
            int d = tid + 256 * q;
            float w = Wh[d * NC + c];
            sb = fmaf(beta[d], w, sb);
            sw = fmaf(gamma[d], w, sw);
        }
        redb[tid] = sb; redw[tid] = sw;
        __syncthreads();
        for (int st = 128; st > 0; st >>= 1) {
            if (tid < st) { redb[tid] += redb[tid + st]; redw[tid] += redw[tid + st]; }
            __syncthreads();
        }
        if (tid == 0) { bias2[c] = bh[c] + redb[0]; wsum[c] = redw[0]; }
    }
}

// -------- fused: swapped phase-1 MFMA puts one table row per lane; phase 2/3
// fused per head with LN folded into the epilogue. LDS = 32KB stage only.
// __launch_bounds__(256,3): unified VGPR+AGPR cap 170 — accG(64 AGPR) +
// accO(12 AGPR) + afr/ya/temps (~72 VGPR) fit WITHOUT spill. (256,4) capped
// at 128 and spilled ~110MB to scratch — the round-1 regression.
__global__ __launch_bounds__(256, 3) void k_fused(
    const float* __restrict__ feats, const float* __restrict__ appd,
    const unsigned short* __restrict__ Wpk,
    const unsigned short* __restrict__ Wgpk,
    const float* __restrict__ vcol,
    const float* __restrict__ b_in,
    const float* __restrict__ bias2,
    const float* __restrict__ wsum,
    float* __restrict__ out)
{
    __shared__ __align__(16) unsigned short stage[16384];   // 32 KB weight staging

    const int tid = threadIdx.x;
    const int wv = tid >> 6;
    const int ln = tid & 63;
    const int quad = ln >> 4;
    const int lr = ln & 15;
    const int j0 = blockIdx.x * 64;
    const int jw = j0 + wv * 16;
    const int ar = min(jw + lr, NROW - 1);

    // ---- preload + pre-pack ALL feat B-fragments (row ar, k = kc*32+quad*8..+7).
    // No HBM loads inside the barrier-fenced loops -> syncthreads drains are L2-only.
    unsigned int afr[8][4];
    {
        const float* rf = feats + (size_t)ar * DIN;
        const float* ra = appd  + (size_t)ar * DIN;
        #pragma unroll
        for (int kc = 0; kc < 8; ++kc) {
            const float* src = (kc < 4) ? rf : ra;
            const int ko = (kc & 3) * 32 + quad * 8;
            float4 x0 = *(const float4*)(src + ko);
            float4 x1 = *(const float4*)(src + ko + 4);
            afr[kc][0] = pk2(x0.x, x0.y);
            afr[kc][1] = pk2(x0.z, x0.w);
            afr[kc][2] = pk2(x1.x, x1.y);
            afr[kc][3] = pk2(x1.z, x1.w);
        }
    }
    float vm[HH];
    #pragma unroll
    for (int h = 0; h < HH; ++h) vm[h] = vcol[h * NROW + ar];

    const f32x4 zero4 = {0.f, 0.f, 0.f, 0.f};
    f32x4 accG[16];
    #pragma unroll
    for (int t = 0; t < 16; ++t) accG[t] = zero4;

    // ---- phase 1: G = feat @ Win, SWAPPED operands: mfma(Wfrag, featfrag).
    // Result layout: lane(quad,lr) holds G[row jw+lr][col 16t + quad*4 + rg].
    // 4 chunks x 32 frags (32KB), 2 barriers each.
    #pragma unroll 1
    for (int cc = 0; cc < 4; ++cc) {
        __syncthreads();   // previous chunk's LDS reads done
        #pragma unroll
        for (int q = 0; q < 8; ++q) {
            int f = wv * 8 + q;
            gl_lds16(Wpk + ((size_t)((cc * 32 + f) * 64 + ln)) * 8, &stage[f * 512]);
        }
        __syncthreads();   // staging complete (only gl_lds outstanding: L2 latency)
        #pragma unroll
        for (int kcl = 0; kcl < 2; ++kcl) {
            union { unsigned int ui[4]; bf16x8 v; } a;
            a.ui[0] = afr[cc * 2 + kcl][0];
            a.ui[1] = afr[cc * 2 + kcl][1];
            a.ui[2] = afr[cc * 2 + kcl][2];
            a.ui[3] = afr[cc * 2 + kcl][3];
            #pragma unroll
            for (int t = 0; t < 16; ++t) {
                bf16x8 wf = *(const bf16x8*)&stage[((kcl * 16 + t) * 64 + ln) * 8];
                accG[t] = __builtin_amdgcn_mfma_f32_16x16x32_bf16(wf, a.v, accG[t], 0, 0, 0);
            }
        }
    }

    // ---- phase 2+3 fused per head: y = vm*relu(vm*G + b) computed ONCE (f32 G),
    // stats accumulated inline, packed to bf16, fed straight to the head GEMM
    // (pi-permuted Wgpk makes the A-fragment = lane's packed words in order).
    // LN applied in the epilogue: out = rs*acc + nm*wsum + bias2.
    float s_ = 0.f, ss_ = 0.f;
    f32x4 accO[3];
    #pragma unroll
    for (int t = 0; t < 3; ++t) accO[t] = zero4;

    #pragma unroll 1
    for (int h = 0; h < HH; ++h) {
        __syncthreads();   // stage buffer free
        #pragma unroll
        for (int q = 0; q < 6; ++q) {
            int sl = wv * 6 + q;
            gl_lds16(Wgpk + ((size_t)((h * 24 + sl) * 64 + ln)) * 8, &stage[sl * 512]);
        }
        const float vh = vm[h];
        unsigned int ya[16];
        // pass 0: t = 0..8 (covers kc' 0..4); VALU here hides the staging latency
        #pragma unroll
        for (int tt = 0; tt < 8; ++tt) {
            float4 b4 = *(const float4*)&b_in[tt * 16 + quad * 4];
            float y0 = vh * fmaxf(fmaf(vh, accG[tt][0], b4.x), 0.f);
            float y1 = vh * fmaxf(fmaf(vh, accG[tt][1], b4.y), 0.f);
            float y2 = vh * fmaxf(fmaf(vh, accG[tt][2], b4.z), 0.f);
            float y3 = vh * fmaxf(fmaf(vh, accG[tt][3], b4.w), 0.f);
            s_ += (y0 + y1) + (y2 + y3);
            ss_ = fmaf(y0, y0, ss_); ss_ = fmaf(y1, y1, ss_);
            ss_ = fmaf(y2, y2, ss_); ss_ = fmaf(y3, y3, ss_);
            ya[tt * 2]     = pk2(y0, y1);
            ya[tt * 2 + 1] = pk2(y2, y3);
        }
        __syncthreads();   // staging landed
        #pragma unroll
        for (int kcl = 0; kcl < 4; ++kcl) {
            union { unsigned int ui[4]; bf16x8 v; } af;
            af.ui[0] = ya[4 * kcl];     af.ui[1] = ya[4 * kcl + 1];
            af.ui[2] = ya[4 * kcl + 2]; af.ui[3] = ya[4 * kcl + 3];
            #pragma unroll
            for (int t3 = 0; t3 < 3; ++t3) {
                bf16x8 wf = *(const bf16x8*)&stage[((kcl * 3 + t3) * 64 + ln) * 8];
                accO[t3] = __builtin_amdgcn_mfma_f32_16x16x32_bf16(af.v, wf, accO[t3], 0, 0, 0);
            }
        }
        // pass 1: t = 8..16 (kc' 4..8); overlaps with pass-0 MFMAs on the matrix pipe
        #pragma unroll
        for (int tt = 8; tt < 16; ++tt) {
            float4 b4 = *(const float4*)&b_in[tt * 16 + quad * 4];
            float y0 = vh * fmaxf(fmaf(vh, accG[tt][0], b4.x), 0.f);
            float y1 = vh * fmaxf(fmaf(vh, accG[tt][1], b4.y), 0.f);
            float y2 = vh * fmaxf(fmaf(vh, accG[tt][2], b4.z), 0.f);
            float y3 = vh * fmaxf(fmaf(vh, accG[tt][3], b4.w), 0.f);
            s_ += (y0 + y1) + (y2 + y3);
            ss_ = fmaf(y0, y0, ss_); ss_ = fmaf(y1, y1, ss_);
            ss_ = fmaf(y2, y2, ss_); ss_ = fmaf(y3, y3, ss_);
            ya[(tt - 8) * 2]     = pk2(y0, y1);
            ya[(tt - 8) * 2 + 1] = pk2(y2, y3);
        }
        #pragma unroll
        for (int kcl = 4; kcl < 8; ++kcl) {
            union { unsigned int ui[4]; bf16x8 v; } af;
            af.ui[0] = ya[4 * (kcl - 4)];     af.ui[1] = ya[4 * (kcl - 4) + 1];
            af.ui[2] = ya[4 * (kcl - 4) + 2]; af.ui[3] = ya[4 * (kcl - 4) + 3];
            #pragma unroll
            for (int t3 = 0; t3 < 3; ++t3) {
                bf16x8 wf = *(const bf16x8*)&stage[((kcl * 3 + t3) * 64 + ln) * 8];
                accO[t3] = __builtin_amdgcn_mfma_f32_16x16x32_bf16(af.v, wf, accO[t3], 0, 0, 0);
            }
        }
    }

    // ---- epilogue: finish LN stats (row = jw+lr lives on the 4 quad-lanes of lr),
    // fold LN affine: out = rs*acc + nm*wsum + bias2
    s_  += __shfl_xor(s_, 16);  s_  += __shfl_xor(s_, 32);
    ss_ += __shfl_xor(ss_, 16); ss_ += __shfl_xor(ss_, 32);
    float mm  = s_ * (1.f / 1024.f);
    float var = ss_ * (1.f / 1024.f) - mm * mm;
    float rs  = rsqrtf(var + 1e-5f);
    float nm  = -mm * rs;

    float rs_r[4], nm_r[4];
    #pragma unroll
    for (int rg = 0; rg < 4; ++rg) {
        int rloc = quad * 4 + rg;          // lane rloc (quad 0, lr=rloc) has row jw+rloc
        rs_r[rg] = __shfl(rs, rloc);
        nm_r[rg] = __shfl(nm, rloc);
    }
    #pragma unroll
    for (int t = 0; t < 3; ++t) {
        int c = t * 16 + lr;
        if (c < NC) {
            float w2 = wsum[c], b2 = bias2[c];
            #pragma unroll
            for (int rg = 0; rg < 4; ++rg) {
                int row = jw + quad * 4 + rg;
                if (row < NROW)
                    out[(size_t)row * NC + c] = fmaf(rs_r[rg], accO[t][rg], fmaf(nm_r[rg], w2, b2));
            }
        }
    }
}

extern "C" void kernel_launch(void* const* d_in, const int* in_sizes, int n_in,
                              void* d_out, int out_size, void* d_ws, size_t ws_size,
                              hipStream_t stream) {
    const int*   pi    = (const int*)d_in[0];
    const float* pv    = (const float*)d_in[1];
    const float* feats = (const float*)d_in[2];
    const float* appd  = (const float*)d_in[3];
    const float* Win   = (const float*)d_in[4];
    const float* b_in  = (const float*)d_in[5];
    const float* gamma = (const float*)d_in[6];
    const float* beta  = (const float*)d_in[7];
    const float* Wh    = (const float*)d_in[8];
    const float* bh    = (const float*)d_in[9];
    float* out = (float*)d_out;

    char* w = (char*)d_ws;
    float*          vcolW  = (float*)w;                        // 800000 B
    unsigned short* WpkW   = (unsigned short*)(w + 800000);    // 131072 B
    unsigned short* WgpkW  = (unsigned short*)(w + 931072);    // 98304 B
    float*          bias2W = (float*)(w + 1029376);            // 160 B
    float*          wsumW  = (float*)(w + 1029536);            // 160 B

    k_prep<<<850, 256, 0, stream>>>(pi, pv, Win, Wh, gamma, beta, bh,
                                    vcolW, WpkW, WgpkW, bias2W, wsumW);
    k_fused<<<NBLK, 256, 0, stream>>>(feats, appd, WpkW, WgpkW, vcolW, b_in,
                                      bias2W, wsumW, out);
}

// Round 3
// 168.783 us; speedup vs baseline: 1.1886x; 1.0861x over previous
//
#include <hip/hip_runtime.h>
#include <hip/hip_bf16.h>

#define NROW 50000
#define DIN 128
#define DM 256
#define HH 4
#define NC 40
#define BHN 200000
#define NBLK 782   // ceil(50000/64): 64 rows per 4-wave block

typedef float f32x4 __attribute__((ext_vector_type(4)));
typedef short bf16x8 __attribute__((ext_vector_type(8)));

__device__ __forceinline__ unsigned int pk2(float lo, float hi) {
    __hip_bfloat162 h = __float22bfloat162_rn(make_float2(lo, hi));
    return *(unsigned int*)&h;
}

// async 16B/lane global->LDS: lds dest = wave-uniform base + lane*16
__device__ __forceinline__ void gl_lds16(const unsigned short* g, unsigned short* l) {
    __builtin_amdgcn_global_load_lds(
        (const __attribute__((address_space(1))) unsigned int*)(g),
        (__attribute__((address_space(3))) unsigned int*)(l),
        16, 0, 0);
}

// -------- prep: [0,782) scatter | [782,798) Wpk | [798,810) Wgpk | [810,850) bias2+wsum --------
// Wpk  [kc][t][ln][8]: fragment-packed Win^T (A operand of swapped phase-1 MFMA).
// Wgpk [h][kc][t][ln][8]: fragment-packed gamma*Wh^T, pi-permuted k so the phase-3
//   A-fragment equals the lane-local packed Y words in natural order.
__global__ __launch_bounds__(256) void k_prep(const int* __restrict__ pi,
                                              const float* __restrict__ pv,
                                              const float* __restrict__ Win,
                                              const float* __restrict__ Wh,
                                              const float* __restrict__ gamma,
                                              const float* __restrict__ beta,
                                              const float* __restrict__ bh,
                                              float* __restrict__ vcol,
                                              unsigned short* __restrict__ Wpk,
                                              unsigned short* __restrict__ Wgpk,
                                              float* __restrict__ bias2,
                                              float* __restrict__ wsum) {
    const int bid = blockIdx.x, tid = threadIdx.x;
    if (bid < 782) {
        int k = bid * 256 + tid;
        if (k < BHN) {
            int b = (k >= 150000) ? 3 : (k >= 100000) ? 2 : (k >= 50000) ? 1 : 0;
            int col = pi[2 * BHN + k];
            vcol[b * NROW + col] = pv[k];
        }
    } else if (bid < 798) {
        int base = (bid - 782) * 512;
        #pragma unroll
        for (int qq = 0; qq < 2; ++qq) {
            int s = base + qq * 256 + tid;
            int ln = s & 63;
            int t  = (s >> 6) & 15;
            int kc = s >> 10;
            int n  = t * 16 + (ln & 15);
            int kb = kc * 32 + ((ln >> 4) << 3);
            union { unsigned int ui[4]; uint4 v4; } u;
            #pragma unroll
            for (int jj = 0; jj < 4; ++jj)
                u.ui[jj] = pk2(Win[(kb + 2 * jj) * DM + n], Win[(kb + 2 * jj + 1) * DM + n]);
            *(uint4*)&Wpk[s * 8] = u.v4;
        }
    } else if (bid < 810) {
        int base = (bid - 798) * 512;
        #pragma unroll
        for (int qq = 0; qq < 2; ++qq) {
            int s = base + qq * 256 + tid;
            int ln = s & 63;
            int u6 = s >> 6;
            int t  = u6 % 3;
            int v6 = u6 / 3;
            int kc = v6 & 7;
            int h  = v6 >> 3;
            int c  = t * 16 + (ln & 15);
            int dbase = h * 256 + kc * 32 + ((ln >> 4) << 2);   // h*256 + 32*kc + 4*q
            union { unsigned int ui[4]; uint4 v4; } u;
            if (c < NC) {
                #pragma unroll
                for (int jj = 0; jj < 4; ++jj) {
                    int dA = dbase + ((jj >> 1) << 4) + ((jj & 1) << 1);  // pi row for k-slot 2jj
                    u.ui[jj] = pk2(gamma[dA] * Wh[dA * NC + c],
                                   gamma[dA + 1] * Wh[(dA + 1) * NC + c]);
                }
            } else {
                u.v4 = make_uint4(0u, 0u, 0u, 0u);
            }
            *(uint4*)&Wgpk[s * 8] = u.v4;
        }
    } else {   // bias2[c] = bh[c] + sum_d beta[d]*Wh[d][c] ; wsum[c] = sum_d gamma[d]*Wh[d][c]
        __shared__ float redb[256], redw[256];
        int c = bid - 810;
        float sb = 0.f, sw = 0.f;
        #pragma unroll
        for (int q = 0; q < 4; ++q) {
            int d = tid + 256 * q;
            float w = Wh[d * NC + c];
            sb = fmaf(beta[d], w, sb);
            sw = fmaf(gamma[d], w, sw);
        }
        redb[tid] = sb; redw[tid] = sw;
        __syncthreads();
        for (int st = 128; st > 0; st >>= 1) {
            if (tid < st) { redb[tid] += redb[tid + st]; redw[tid] += redw[tid + st]; }
            __syncthreads();
        }
        if (tid == 0) { bias2[c] = bh[c] + redb[0]; wsum[c] = redw[0]; }
    }
}

// y-pass for head H over this half's 8 accG fragments: computes y once (f32),
// accumulates LN stats, packs to bf16 words ya[] (A-fragment order via pi-perm).
#define Y_PASS(H, HALF) { \
    const float vh = vm[H]; \
    _Pragma("unroll") \
    for (int tt = 0; tt < 8; ++tt) { \
        float4 b4 = *(const float4*)&b_in[((HALF) * 8 + tt) * 16 + quad * 4]; \
        float y0 = vh * fmaxf(fmaf(vh, accG[tt][0], b4.x), 0.f); \
        float y1 = vh * fmaxf(fmaf(vh, accG[tt][1], b4.y), 0.f); \
        float y2 = vh * fmaxf(fmaf(vh, accG[tt][2], b4.z), 0.f); \
        float y3 = vh * fmaxf(fmaf(vh, accG[tt][3], b4.w), 0.f); \
        s_ += (y0 + y1) + (y2 + y3); \
        ss_ = fmaf(y0, y0, ss_); ss_ = fmaf(y1, y1, ss_); \
        ss_ = fmaf(y2, y2, ss_); ss_ = fmaf(y3, y3, ss_); \
        ya[tt * 2]     = pk2(y0, y1); \
        ya[tt * 2 + 1] = pk2(y2, y3); \
    } }

// 12 MFMAs for head H (this half's 4 k-chunks x 3 col-frags) from staged Wg slots.
#define HEAD_MFMA(H) { \
    _Pragma("unroll") \
    for (int kcl = 0; kcl < 4; ++kcl) { \
        union { unsigned int ui[4]; bf16x8 v; } af; \
        af.ui[0] = ya[4 * kcl];     af.ui[1] = ya[4 * kcl + 1]; \
        af.ui[2] = ya[4 * kcl + 2]; af.ui[3] = ya[4 * kcl + 3]; \
        _Pragma("unroll") \
        for (int t3 = 0; t3 < 3; ++t3) { \
            bf16x8 wf = *(const bf16x8*)&stage[((((H) & 1) * 12 + kcl * 3 + t3) * 64 + ln) * 8]; \
            accO[t3] = __builtin_amdgcn_mfma_f32_16x16x32_bf16(af.v, wf, accO[t3], 0, 0, 0); \
        } } }

// -------- fused. FULLY UNROLLED: no runtime-indexed register arrays (rule #20 —
// R2's #pragma unroll 1 loops put afr/vm in scratch: 64MB r/w spill traffic).
// DM split into two 128-col halves: accG 8 frags (32 AGPR) instead of 16 (64),
// phase-2/3 fused per half. Staging double-buffered in 16KB sub-buffers so every
// barrier drain waits on loads that already had a compute phase in flight. --------
__global__ __launch_bounds__(256, 3) void k_fused(
    const float* __restrict__ feats, const float* __restrict__ appd,
    const unsigned short* __restrict__ Wpk,
    const unsigned short* __restrict__ Wgpk,
    const float* __restrict__ vcol,
    const float* __restrict__ b_in,
    const float* __restrict__ bias2,
    const float* __restrict__ wsum,
    float* __restrict__ out)
{
    __shared__ __align__(16) unsigned short stage[16384];   // 32 KB (2 x 16 KB sub-buffers)

    const int tid = threadIdx.x;
    const int wv = tid >> 6;
    const int ln = tid & 63;
    const int quad = ln >> 4;
    const int lr = ln & 15;
    const int jw = blockIdx.x * 64 + wv * 16;
    const int ar = min(jw + lr, NROW - 1);

    // issue half-0 chunk-0 Wpk staging immediately (stage buffer free at start);
    // feat packing below hides its latency.
    #pragma unroll
    for (int q = 0; q < 4; ++q) {
        int f = wv * 4 + q;                       // kc = f>>3 in {0,1}, th = f&7, t = th
        gl_lds16(Wpk + ((size_t)(((f >> 3) * 16 + (f & 7)) * 64 + ln)) * 8, &stage[f * 512]);
    }

    // ---- prologue: pack ALL feat B-fragments into registers (static indexing only)
    unsigned int afr[8][4];
    {
        const float* rf = feats + (size_t)ar * DIN;
        const float* ra = appd  + (size_t)ar * DIN;
        #pragma unroll
        for (int kc = 0; kc < 8; ++kc) {
            const float* src = (kc < 4) ? rf : ra;
            const int ko = (kc & 3) * 32 + quad * 8;
            float4 x0 = *(const float4*)(src + ko);
            float4 x1 = *(const float4*)(src + ko + 4);
            afr[kc][0] = pk2(x0.x, x0.y);
            afr[kc][1] = pk2(x0.z, x0.w);
            afr[kc][2] = pk2(x1.x, x1.y);
            afr[kc][3] = pk2(x1.z, x1.w);
        }
    }
    float vm[HH];
    #pragma unroll
    for (int h = 0; h < HH; ++h) vm[h] = vcol[h * NROW + ar];

    const f32x4 zero4 = {0.f, 0.f, 0.f, 0.f};
    float s_ = 0.f, ss_ = 0.f;
    f32x4 accO[3];
    #pragma unroll
    for (int t = 0; t < 3; ++t) accO[t] = zero4;
    f32x4 accG[8];
    unsigned int ya[16];

    #pragma unroll
    for (int half = 0; half < 2; ++half) {
        // ---- phase 1 (this half): G cols [half*128, half*128+128), 4 pipelined chunks
        // chunk c: kc in {2c, 2c+1} x th 0..8 -> 16 frags in sub-buffer (c&1).
        #pragma unroll
        for (int c = 0; c < 4; ++c) {
            __syncthreads();                      // chunk c staged (drain)
            if (c < 3) {                          // issue chunk c+1 into the other sub-buffer
                #pragma unroll
                for (int q = 0; q < 4; ++q) {
                    int f = wv * 4 + q;
                    int kc = 2 * (c + 1) + (f >> 3), th = f & 7;
                    gl_lds16(Wpk + ((size_t)((kc * 16 + half * 8 + th) * 64 + ln)) * 8,
                             &stage[((c + 1) & 1) * 8192 + f * 512]);
                }
            }
            #pragma unroll
            for (int kcl = 0; kcl < 2; ++kcl) {
                union { unsigned int ui[4]; bf16x8 v; } a;
                a.ui[0] = afr[2 * c + kcl][0]; a.ui[1] = afr[2 * c + kcl][1];
                a.ui[2] = afr[2 * c + kcl][2]; a.ui[3] = afr[2 * c + kcl][3];
                #pragma unroll
                for (int th = 0; th < 8; ++th) {
                    bf16x8 wf = *(const bf16x8*)&stage[(c & 1) * 8192 + ((kcl * 8 + th) * 64 + ln) * 8];
                    accG[th] = __builtin_amdgcn_mfma_f32_16x16x32_bf16(
                        wf, a.v, (c == 0 && kcl == 0) ? zero4 : accG[th], 0, 0, 0);
                }
            }
        }
        __syncthreads();                          // chunk-3 reads done; stage free

        // ---- phase 2+3 (this half): heads in pairs; Wg chunk = 2 heads x 4 kc x 3 = 24 frags
        #pragma unroll
        for (int hp = 0; hp < 2; ++hp) {
            #pragma unroll
            for (int q = 0; q < 6; ++q) {
                int f = wv * 6 + q;
                int hl = f / 12, rem = f % 12, kcr = rem / 3, t3 = rem % 3;
                int h = 2 * hp + hl;
                gl_lds16(Wgpk + ((size_t)(((h * 8 + half * 4 + kcr) * 3 + t3) * 64 + ln)) * 8,
                         &stage[f * 512]);
            }
            if (hp == 0) { Y_PASS(0, half) } else { Y_PASS(2, half) }   // hides Wg latency
            __syncthreads();                      // Wg chunk staged
            if (hp == 0) {
                HEAD_MFMA(0)
                Y_PASS(1, half)
                HEAD_MFMA(1)
            } else {
                HEAD_MFMA(2)
                Y_PASS(3, half)
                HEAD_MFMA(3)
            }
            __syncthreads();                      // Wg reads done before slots reused
        }
        if (half == 0) {                          // issue next half's chunk 0 (slots free now)
            #pragma unroll
            for (int q = 0; q < 4; ++q) {
                int f = wv * 4 + q;
                gl_lds16(Wpk + ((size_t)(((f >> 3) * 16 + 8 + (f & 7)) * 64 + ln)) * 8,
                         &stage[f * 512]);
            }
        }
    }

    // ---- epilogue: finish LN stats (row jw+lr partials live on the 4 quad-lanes of lr),
    // fold LN affine: out = rs*acc + nm*wsum + bias2
    s_  += __shfl_xor(s_, 16);  s_  += __shfl_xor(s_, 32);
    ss_ += __shfl_xor(ss_, 16); ss_ += __shfl_xor(ss_, 32);
    float mm  = s_ * (1.f / 1024.f);
    float var = ss_ * (1.f / 1024.f) - mm * mm;
    float rs  = rsqrtf(var + 1e-5f);
    float nm  = -mm * rs;

    float rs_r[4], nm_r[4];
    #pragma unroll
    for (int rg = 0; rg < 4; ++rg) {
        int rloc = quad * 4 + rg;                 // lane rloc (quad 0, lr=rloc) has row jw+rloc
        rs_r[rg] = __shfl(rs, rloc);
        nm_r[rg] = __shfl(nm, rloc);
    }
    #pragma unroll
    for (int t = 0; t < 3; ++t) {
        int c = t * 16 + lr;
        if (c < NC) {
            float w2 = wsum[c], b2 = bias2[c];
            #pragma unroll
            for (int rg = 0; rg < 4; ++rg) {
                int row = jw + quad * 4 + rg;
                if (row < NROW)
                    out[(size_t)row * NC + c] = fmaf(rs_r[rg], accO[t][rg], fmaf(nm_r[rg], w2, b2));
            }
        }
    }
}

extern "C" void kernel_launch(void* const* d_in, const int* in_sizes, int n_in,
                              void* d_out, int out_size, void* d_ws, size_t ws_size,
                              hipStream_t stream) {
    const int*   pi    = (const int*)d_in[0];
    const float* pv    = (const float*)d_in[1];
    const float* feats = (const float*)d_in[2];
    const float* appd  = (const float*)d_in[3];
    const float* Win   = (const float*)d_in[4];
    const float* b_in  = (const float*)d_in[5];
    const float* gamma = (const float*)d_in[6];
    const float* beta  = (const float*)d_in[7];
    const float* Wh    = (const float*)d_in[8];
    const float* bh    = (const float*)d_in[9];
    float* out = (float*)d_out;

    char* w = (char*)d_ws;
    float*          vcolW  = (float*)w;                        // 800000 B
    unsigned short* WpkW   = (unsigned short*)(w + 800000);    // 131072 B
    unsigned short* WgpkW  = (unsigned short*)(w + 931072);    // 98304 B
    float*          bias2W = (float*)(w + 1029376);            // 160 B
    float*          wsumW  = (float*)(w + 1029536);            // 160 B

    k_prep<<<850, 256, 0, stream>>>(pi, pv, Win, Wh, gamma, beta, bh,
                                    vcolW, WpkW, WgpkW, bias2W, wsumW);
    k_fused<<<NBLK, 256, 0, stream>>>(feats, appd, WpkW, WgpkW, vcolW, b_in,
                                      bias2W, wsumW, out);
}

// Round 4
// 146.745 us; speedup vs baseline: 1.3671x; 1.1502x over previous
//
#include <hip/hip_runtime.h>
#include <hip/hip_bf16.h>

#define NROW 50000
#define DIN 128
#define DM 256
#define HH 4
#define NC 40
#define BHN 200000
#define NBLK 782   // ceil(50000/64): 64 rows per 4-wave block

typedef float f32x4 __attribute__((ext_vector_type(4)));
typedef short bf16x8 __attribute__((ext_vector_type(8)));

__device__ __forceinline__ unsigned int pk2(float lo, float hi) {
    __hip_bfloat162 h = __float22bfloat162_rn(make_float2(lo, hi));
    return *(unsigned int*)&h;
}

// async 16B/lane global->LDS: lds dest = wave-uniform base + lane*16
__device__ __forceinline__ void gl_lds16(const unsigned short* g, unsigned short* l) {
    __builtin_amdgcn_global_load_lds(
        (const __attribute__((address_space(1))) unsigned int*)(g),
        (__attribute__((address_space(3))) unsigned int*)(l),
        16, 0, 0);
}

// -------- prep: [0,196) scatter x4 | [196,212) Wpk | [212,224) Wgpk | [224,264) bias2+wsum --------
// Wpk  [kc][t][ln][8]: fragment-packed Win^T (A operand of swapped phase-1 MFMA).
// Wgpk [h][kc][t][ln][8]: fragment-packed gamma*Wh^T, pi-permuted k so the phase-3
//   A-fragment equals the lane-local packed Y words in natural order.
__global__ __launch_bounds__(256) void k_prep(const int* __restrict__ pi,
                                              const float* __restrict__ pv,
                                              const float* __restrict__ Win,
                                              const float* __restrict__ Wh,
                                              const float* __restrict__ gamma,
                                              const float* __restrict__ beta,
                                              const float* __restrict__ bh,
                                              float* __restrict__ vcol,
                                              unsigned short* __restrict__ Wpk,
                                              unsigned short* __restrict__ Wgpk,
                                              float* __restrict__ bias2,
                                              float* __restrict__ wsum) {
    const int bid = blockIdx.x, tid = threadIdx.x;
    if (bid < 196) {
        // vectorized scatter: 4 elements/thread; BHN%4==0 and 50000%4==0 so the
        // 4-group never straddles a batch boundary -> one b for all 4.
        int k4 = (bid * 256 + tid) * 4;
        if (k4 < BHN) {
            int4   c4 = *(const int4*)&pi[2 * BHN + k4];
            float4 v4 = *(const float4*)&pv[k4];
            int b = (k4 >= 150000) ? 3 : (k4 >= 100000) ? 2 : (k4 >= 50000) ? 1 : 0;
            float* vb = vcol + b * NROW;
            vb[c4.x] = v4.x; vb[c4.y] = v4.y; vb[c4.z] = v4.z; vb[c4.w] = v4.w;
        }
    } else if (bid < 212) {
        int base = (bid - 196) * 512;
        #pragma unroll
        for (int qq = 0; qq < 2; ++qq) {
            int s = base + qq * 256 + tid;
            int ln = s & 63;
            int t  = (s >> 6) & 15;
            int kc = s >> 10;
            int n  = t * 16 + (ln & 15);
            int kb = kc * 32 + ((ln >> 4) << 3);
            union { unsigned int ui[4]; uint4 v4; } u;
            #pragma unroll
            for (int jj = 0; jj < 4; ++jj)
                u.ui[jj] = pk2(Win[(kb + 2 * jj) * DM + n], Win[(kb + 2 * jj + 1) * DM + n]);
            *(uint4*)&Wpk[s * 8] = u.v4;
        }
    } else if (bid < 224) {
        int base = (bid - 212) * 512;
        #pragma unroll
        for (int qq = 0; qq < 2; ++qq) {
            int s = base + qq * 256 + tid;
            int ln = s & 63;
            int u6 = s >> 6;
            int t  = u6 % 3;
            int v6 = u6 / 3;
            int kc = v6 & 7;
            int h  = v6 >> 3;
            int c  = t * 16 + (ln & 15);
            int dbase = h * 256 + kc * 32 + ((ln >> 4) << 2);   // h*256 + 32*kc + 4*q
            union { unsigned int ui[4]; uint4 v4; } u;
            if (c < NC) {
                #pragma unroll
                for (int jj = 0; jj < 4; ++jj) {
                    int dA = dbase + ((jj >> 1) << 4) + ((jj & 1) << 1);  // pi row for k-slot 2jj
                    u.ui[jj] = pk2(gamma[dA] * Wh[dA * NC + c],
                                   gamma[dA + 1] * Wh[(dA + 1) * NC + c]);
                }
            } else {
                u.v4 = make_uint4(0u, 0u, 0u, 0u);
            }
            *(uint4*)&Wgpk[s * 8] = u.v4;
        }
    } else {   // bias2[c] = bh[c] + sum_d beta[d]*Wh[d][c] ; wsum[c] = sum_d gamma[d]*Wh[d][c]
        __shared__ float redb[256], redw[256];
        int c = bid - 224;
        float sb = 0.f, sw = 0.f;
        #pragma unroll
        for (int q = 0; q < 4; ++q) {
            int d = tid + 256 * q;
            float w = Wh[d * NC + c];
            sb = fmaf(beta[d], w, sb);
            sw = fmaf(gamma[d], w, sw);
        }
        redb[tid] = sb; redw[tid] = sw;
        __syncthreads();
        for (int st = 128; st > 0; st >>= 1) {
            if (tid < st) { redb[tid] += redb[tid + st]; redw[tid] += redw[tid + st]; }
            __syncthreads();
        }
        if (tid == 0) { bias2[c] = bh[c] + redb[0]; wsum[c] = redw[0]; }
    }
}

// y-pass for head H over this half's 8 accG fragments: computes y once (f32),
// accumulates LN stats, packs to bf16 words ya[] (A-fragment order via pi-perm).
// bias read from LDS (bshm) per pass: keeps b_in OUT of long-lived registers.
#define Y_PASS(H, HALF) { \
    const float vh = vm[H]; \
    _Pragma("unroll") \
    for (int tt = 0; tt < 8; ++tt) { \
        float4 b4 = *(const float4*)&bshm[((HALF) * 8 + tt) * 16 + quad * 4]; \
        float y0 = vh * fmaxf(fmaf(vh, accG[tt][0], b4.x), 0.f); \
        float y1 = vh * fmaxf(fmaf(vh, accG[tt][1], b4.y), 0.f); \
        float y2 = vh * fmaxf(fmaf(vh, accG[tt][2], b4.z), 0.f); \
        float y3 = vh * fmaxf(fmaf(vh, accG[tt][3], b4.w), 0.f); \
        s_ += (y0 + y1) + (y2 + y3); \
        ss_ = fmaf(y0, y0, ss_); ss_ = fmaf(y1, y1, ss_); \
        ss_ = fmaf(y2, y2, ss_); ss_ = fmaf(y3, y3, ss_); \
        ya[tt * 2]     = pk2(y0, y1); \
        ya[tt * 2 + 1] = pk2(y2, y3); \
    } }

// 12 MFMAs for head H (this half's 4 k-chunks x 3 col-frags) from staged Wg slots.
#define HEAD_MFMA(H) { \
    _Pragma("unroll") \
    for (int kcl = 0; kcl < 4; ++kcl) { \
        union { unsigned int ui[4]; bf16x8 v; } af; \
        af.ui[0] = ya[4 * kcl];     af.ui[1] = ya[4 * kcl + 1]; \
        af.ui[2] = ya[4 * kcl + 2]; af.ui[3] = ya[4 * kcl + 3]; \
        _Pragma("unroll") \
        for (int t3 = 0; t3 < 3; ++t3) { \
            bf16x8 wf = *(const bf16x8*)&stage[((((H) & 1) * 12 + kcl * 3 + t3) * 64 + ln) * 8]; \
            accO[t3] = __builtin_amdgcn_mfma_f32_16x16x32_bf16(af.v, wf, accO[t3], 0, 0, 0); \
        } } }

// -------- fused. Live-range discipline (R3 spilled 51MB of WRITE despite static
// indexing): afr is PER-HALF (re-packed from L2-hot feats at half 1 -> not live
// through phase 2/3), b_in served from LDS (not CSE'd into registers). Peak live
// ~110 regs < 170 cap at __launch_bounds__(256,3). --------
__global__ __launch_bounds__(256, 3) void k_fused(
    const float* __restrict__ feats, const float* __restrict__ appd,
    const unsigned short* __restrict__ Wpk,
    const unsigned short* __restrict__ Wgpk,
    const float* __restrict__ vcol,
    const float* __restrict__ b_in,
    const float* __restrict__ bias2,
    const float* __restrict__ wsum,
    float* __restrict__ out)
{
    __shared__ __align__(16) unsigned short stage[16384];   // 32 KB (2 x 16 KB sub-buffers)
    __shared__ __align__(16) float bshm[256];               // b_in, LDS-resident

    const int tid = threadIdx.x;
    const int wv = tid >> 6;
    const int ln = tid & 63;
    const int quad = ln >> 4;
    const int lr = ln & 15;
    const int jw = blockIdx.x * 64 + wv * 16;
    const int ar = min(jw + lr, NROW - 1);

    // issue half-0 chunk-0 Wpk staging immediately; prologue work hides its latency
    #pragma unroll
    for (int q = 0; q < 4; ++q) {
        int f = wv * 4 + q;                       // kc = f>>3, th = f&7
        gl_lds16(Wpk + ((size_t)(((f >> 3) * 16 + (f & 7)) * 64 + ln)) * 8, &stage[f * 512]);
    }
    bshm[tid] = b_in[tid];                        // visible after first barrier

    float vm[HH];
    #pragma unroll
    for (int h = 0; h < HH; ++h) vm[h] = vcol[h * NROW + ar];

    const f32x4 zero4 = {0.f, 0.f, 0.f, 0.f};
    float s_ = 0.f, ss_ = 0.f;
    f32x4 accO[3];
    #pragma unroll
    for (int t = 0; t < 3; ++t) accO[t] = zero4;
    f32x4 accG[8];
    unsigned int ya[16];

    #pragma unroll
    for (int half = 0; half < 2; ++half) {
        // compiler fence: forbid CSE of half-1's afr loads with half-0's
        // (otherwise afr stays live through phase 2/3 -> the R3 spill)
        if (half == 1) asm volatile("" ::: "memory");

        // ---- per-half afr pack (live only during this half's phase 1)
        unsigned int afr[8][4];
        {
            const float* rf = feats + (size_t)ar * DIN;
            const float* ra = appd  + (size_t)ar * DIN;
            #pragma unroll
            for (int kc = 0; kc < 8; ++kc) {
                const float* src = (kc < 4) ? rf : ra;
                const int ko = (kc & 3) * 32 + quad * 8;
                float4 x0 = *(const float4*)(src + ko);
                float4 x1 = *(const float4*)(src + ko + 4);
                afr[kc][0] = pk2(x0.x, x0.y);
                afr[kc][1] = pk2(x0.z, x0.w);
                afr[kc][2] = pk2(x1.x, x1.y);
                afr[kc][3] = pk2(x1.z, x1.w);
            }
        }

        // ---- phase 1 (this half): G cols [half*128, +128), 4 pipelined chunks.
        // chunk c: kc {2c,2c+1} x th 0..7 -> 16 frags in sub-buffer (c&1).
        #pragma unroll
        for (int c = 0; c < 4; ++c) {
            __syncthreads();                      // chunk c staged (drain)
            if (c < 3) {                          // issue chunk c+1 into other sub-buffer
                #pragma unroll
                for (int q = 0; q < 4; ++q) {
                    int f = wv * 4 + q;
                    int kc = 2 * (c + 1) + (f >> 3), th = f & 7;
                    gl_lds16(Wpk + ((size_t)((kc * 16 + half * 8 + th) * 64 + ln)) * 8,
                             &stage[((c + 1) & 1) * 8192 + f * 512]);
                }
            }
            #pragma unroll
            for (int kcl = 0; kcl < 2; ++kcl) {
                union { unsigned int ui[4]; bf16x8 v; } a;
                a.ui[0] = afr[2 * c + kcl][0]; a.ui[1] = afr[2 * c + kcl][1];
                a.ui[2] = afr[2 * c + kcl][2]; a.ui[3] = afr[2 * c + kcl][3];
                #pragma unroll
                for (int th = 0; th < 8; ++th) {
                    bf16x8 wf = *(const bf16x8*)&stage[(c & 1) * 8192 + ((kcl * 8 + th) * 64 + ln) * 8];
                    accG[th] = __builtin_amdgcn_mfma_f32_16x16x32_bf16(
                        wf, a.v, (c == 0 && kcl == 0) ? zero4 : accG[th], 0, 0, 0);
                }
            }
        }
        __syncthreads();                          // chunk-3 reads done; stage free

        // ---- phase 2+3 (this half): head pairs; Wg chunk = 2 heads x 4 kc x 3 = 24 frags
        #pragma unroll
        for (int hp = 0; hp < 2; ++hp) {
            #pragma unroll
            for (int q = 0; q < 6; ++q) {
                int f = wv * 6 + q;
                int hl = f / 12, rem = f % 12, kcr = rem / 3, t3 = rem % 3;
                int h = 2 * hp + hl;
                gl_lds16(Wgpk + ((size_t)(((h * 8 + half * 4 + kcr) * 3 + t3) * 64 + ln)) * 8,
                         &stage[f * 512]);
            }
            if (hp == 0) { Y_PASS(0, half) } else { Y_PASS(2, half) }   // hides Wg latency
            __syncthreads();                      // Wg chunk staged
            if (hp == 0) {
                HEAD_MFMA(0)
                Y_PASS(1, half)
                HEAD_MFMA(1)
            } else {
                HEAD_MFMA(2)
                Y_PASS(3, half)
                HEAD_MFMA(3)
            }
            __syncthreads();                      // Wg reads done before slots reused
        }
        if (half == 0) {                          // issue half-1 chunk 0 (slots free now);
            #pragma unroll                        // overlaps with half-1's afr repack
            for (int q = 0; q < 4; ++q) {
                int f = wv * 4 + q;
                gl_lds16(Wpk + ((size_t)(((f >> 3) * 16 + 8 + (f & 7)) * 64 + ln)) * 8,
                         &stage[f * 512]);
            }
        }
    }

    // ---- epilogue: finish LN stats (row jw+lr partials live on the 4 quad-lanes of lr),
    // fold LN affine: out = rs*acc + nm*wsum + bias2
    s_  += __shfl_xor(s_, 16);  s_  += __shfl_xor(s_, 32);
    ss_ += __shfl_xor(ss_, 16); ss_ += __shfl_xor(ss_, 32);
    float mm  = s_ * (1.f / 1024.f);
    float var = ss_ * (1.f / 1024.f) - mm * mm;
    float rs  = rsqrtf(var + 1e-5f);
    float nm  = -mm * rs;

    float rs_r[4], nm_r[4];
    #pragma unroll
    for (int rg = 0; rg < 4; ++rg) {
        int rloc = quad * 4 + rg;                 // lane rloc (quad 0, lr=rloc) has row jw+rloc
        rs_r[rg] = __shfl(rs, rloc);
        nm_r[rg] = __shfl(nm, rloc);
    }
    #pragma unroll
    for (int t = 0; t < 3; ++t) {
        int c = t * 16 + lr;
        if (c < NC) {
            float w2 = wsum[c], b2 = bias2[c];
            #pragma unroll
            for (int rg = 0; rg < 4; ++rg) {
                int row = jw + quad * 4 + rg;
                if (row < NROW)
                    out[(size_t)row * NC + c] = fmaf(rs_r[rg], accO[t][rg], fmaf(nm_r[rg], w2, b2));
            }
        }
    }
}

extern "C" void kernel_launch(void* const* d_in, const int* in_sizes, int n_in,
                              void* d_out, int out_size, void* d_ws, size_t ws_size,
                              hipStream_t stream) {
    const int*   pi    = (const int*)d_in[0];
    const float* pv    = (const float*)d_in[1];
    const float* feats = (const float*)d_in[2];
    const float* appd  = (const float*)d_in[3];
    const float* Win   = (const float*)d_in[4];
    const float* b_in  = (const float*)d_in[5];
    const float* gamma = (const float*)d_in[6];
    const float* beta  = (const float*)d_in[7];
    const float* Wh    = (const float*)d_in[8];
    const float* bh    = (const float*)d_in[9];
    float* out = (float*)d_out;

    char* w = (char*)d_ws;
    float*          vcolW  = (float*)w;                        // 800000 B
    unsigned short* WpkW   = (unsigned short*)(w + 800000);    // 131072 B
    unsigned short* WgpkW  = (unsigned short*)(w + 931072);    // 98304 B
    float*          bias2W = (float*)(w + 1029376);            // 160 B
    float*          wsumW  = (float*)(w + 1029536);            // 160 B

    k_prep<<<264, 256, 0, stream>>>(pi, pv, Win, Wh, gamma, beta, bh,
                                    vcolW, WpkW, WgpkW, bias2W, wsumW);
    k_fused<<<NBLK, 256, 0, stream>>>(feats, appd, WpkW, WgpkW, vcolW, b_in,
                                      bias2W, wsumW, out);
}